// Round 7
// baseline (47.898 us; speedup 1.0000x reference)
//
#include <hip/hip_runtime.h>
#include <hip/hip_bf16.h>

// softConLoss: loss = -mean_{i>=10} log_softmax_c( log(s_c(i)/py_c(i)) )[cls_i]
//   s_c(i) = sum_{j != i, cls_j == c} exp(feat_i . feat_j / 0.1)
// R7: fix k_prep quarter-coverage bug (256->1024 blocks); kill union-through-
// memory in pvstep (bit_cast, named scalars); s_setprio around QK MFMAs.

constexpr int NROWS = 8192;
constexpr int DIM   = 128;
constexpr int NCLS  = 10;
constexpr int CS    = 16;       // j-splits (grid.y of k_main)
constexpr int NT    = NROWS / 32;  // 256 j-tiles
constexpr float SCALEF = 14.4269504089f; // (1/TEMP) * log2(e)

typedef __attribute__((ext_vector_type(8)))  short  short8;
typedef __attribute__((ext_vector_type(16))) float  f32x16;
typedef __attribute__((ext_vector_type(4)))  unsigned int uint4v;
typedef unsigned int uint;

// ---- workspace layout (bytes), ~9.9 MB ----
constexpr size_t OFF_FEATU = 0;                                    // bf16 [NROWS][DIM]
constexpr size_t OFF_FEATB = OFF_FEATU + (size_t)NROWS * DIM * 2;  // bf16 [NROWS][DIM] * SCALEF
constexpr size_t OFF_LBFT  = OFF_FEATB + (size_t)NROWS * DIM * 2;  // bf16 [NT][2 jh][2 hi][32 c][8]
constexpr size_t OFF_SLAB  = OFF_LBFT + (size_t)NT * 128 * 16;     // f32 [CS][NCLS][NROWS]
constexpr size_t OFF_DIAG  = OFF_SLAB + (size_t)CS * NCLS * NROWS * 4; // f32 [NROWS]
constexpr size_t OFF_CLS   = OFF_DIAG + (size_t)NROWS * 4;         // int [NROWS]
constexpr size_t OFF_HISTG = OFF_CLS + (size_t)NROWS * 4;          // int [128][NCLS]
constexpr size_t OFF_PART  = OFF_HISTG + (size_t)128 * NCLS * 4;   // f32 [64]
constexpr size_t OFF_CNT   = OFF_PART + 256;                       // int

__device__ inline float exp2a(float x) {
#if __has_builtin(__builtin_amdgcn_exp2f)
  return __builtin_amdgcn_exp2f(x);
#else
  return exp2f(x);
#endif
}

__device__ inline uint pkbf(float a, float b) {  // pack 2 f32 -> dword of 2 bf16
  __hip_bfloat16 ha = __float2bfloat16(a), hb = __float2bfloat16(b);
  return (uint)(*(unsigned short*)&ha) | ((uint)(*(unsigned short*)&hb) << 16);
}

// ---------- kernel 1: conversions + diag + cls + chunk hists + one-hot tiles ----------
// 1024 blocks x 256 thr = 262144 threads (one per float4 of feat — FULL coverage).
__global__ void k_prep(const float* __restrict__ label, const float* __restrict__ feat,
                       __hip_bfloat16* __restrict__ featU, __hip_bfloat16* __restrict__ featB,
                       short8* __restrict__ LbfT, float* __restrict__ diag,
                       int* __restrict__ cls, int* __restrict__ histg,
                       int* __restrict__ counter) {
  const int gid = blockIdx.x * 256 + threadIdx.x;   // [0, 262144)
  const int lane = threadIdx.x & 63;
  {  // featU / featB / diag (32 consecutive threads own one row; DIM/4 = 32)
    int e = gid * 4;
    float4 v = *(const float4*)(feat + e);
    __hip_bfloat16 u0 = __float2bfloat16(v.x), u1 = __float2bfloat16(v.y);
    __hip_bfloat16 u2 = __float2bfloat16(v.z), u3 = __float2bfloat16(v.w);
    __hip_bfloat16 b0 = __float2bfloat16(v.x * SCALEF), b1 = __float2bfloat16(v.y * SCALEF);
    __hip_bfloat16 b2 = __float2bfloat16(v.z * SCALEF), b3 = __float2bfloat16(v.w * SCALEF);
    featU[e + 0] = u0; featU[e + 1] = u1; featU[e + 2] = u2; featU[e + 3] = u3;
    featB[e + 0] = b0; featB[e + 1] = b1; featB[e + 2] = b2; featB[e + 3] = b3;
    float sd = __bfloat162float(u0) * __bfloat162float(b0)
             + __bfloat162float(u1) * __bfloat162float(b1)
             + __bfloat162float(u2) * __bfloat162float(b2)
             + __bfloat162float(u3) * __bfloat162float(b3);
#pragma unroll
    for (int st = 1; st < 32; st <<= 1) sd += __shfl_xor(sd, st, 64);
    // store bf16-rounded: must match exactly what the PV-MFMA accumulated
    if ((gid & 31) == 0) diag[gid >> 5] = __bfloat162float(__float2bfloat16(exp2a(sd)));
  }
  if (gid == 0) *counter = 0;    // reset every call (graph replays)
  if (gid < NROWS) {             // class ids + per-64-row-chunk histograms
    int c = 0;
#pragma unroll
    for (int j = 0; j < NCLS; ++j) if (label[gid * NCLS + j] > 0.5f) c = j;
    cls[gid] = c;
    const int chunk = gid >> 6;
#pragma unroll
    for (int cc = 0; cc < NCLS; ++cc) {
      unsigned long long m = __ballot(c == cc);
      if (lane == cc) histg[chunk * NCLS + cc] = __popcll(m);
    }
  }
  if (gid >= 262144 - 32768) {   // one-hot tiles: [t][jh][hi][c][idx8] bf16
    int w = gid - (262144 - 32768);  // 32768 writers x 16B
    int t = w >> 7, widx = w & 127;
    int jh = widx >> 6, h2 = (widx >> 5) & 1, c = widx & 31;
    int jb = t * 32 + jh * 16 + h2 * 8;
    short8 outv = {0, 0, 0, 0, 0, 0, 0, 0};
    if (c < NCLS) {
#pragma unroll
      for (int m = 0; m < 8; ++m)
        outv[m] = (label[(jb + m) * NCLS + c] > 0.5f) ? (short)0x3F80 : (short)0;
    }
    LbfT[(size_t)t * 128 + widx] = outv;
  }
}

// ---------- kernel 2: main — QK-MFMA -> exp2 -> PV-MFMA vs one-hot ----------
// 256 thr = 4 waves; wave owns 64 i-rows (2 strips of 32) sharing A-frags.
// grid (32 i-blocks, CS j-splits); 16 j-tiles per block, double-buffered LDS.
__device__ inline f32x16 pvstep(const f32x16& D, short8 lt0, short8 lt1, f32x16 O) {
  // exp2 + bf16-pack: 16 f32 -> 8 dwords, all named scalars (reg-resident)
  uint p0 = pkbf(exp2a(D[0]),  exp2a(D[1]));
  uint p1 = pkbf(exp2a(D[2]),  exp2a(D[3]));
  uint p2 = pkbf(exp2a(D[4]),  exp2a(D[5]));
  uint p3 = pkbf(exp2a(D[6]),  exp2a(D[7]));
  uint p4 = pkbf(exp2a(D[8]),  exp2a(D[9]));
  uint p5 = pkbf(exp2a(D[10]), exp2a(D[11]));
  uint p6 = pkbf(exp2a(D[12]), exp2a(D[13]));
  uint p7 = pkbf(exp2a(D[14]), exp2a(D[15]));
  // permlane32_swap(a,b): a' = {a.lo, b.lo}, b' = {a.hi, b.hi} -> A-frag dwords
  asm("v_permlane32_swap_b32 %0, %1" : "+v"(p0), "+v"(p2));
  asm("v_permlane32_swap_b32 %0, %1" : "+v"(p1), "+v"(p3));
  asm("v_permlane32_swap_b32 %0, %1" : "+v"(p4), "+v"(p6));
  asm("v_permlane32_swap_b32 %0, %1" : "+v"(p5), "+v"(p7));
  uint4v q1 = {p0, p1, p2, p3};   // P cols j0..15
  uint4v q2 = {p4, p5, p6, p7};   // P cols j16..31
  O = __builtin_amdgcn_mfma_f32_32x32x16_bf16(__builtin_bit_cast(short8, q1), lt0, O, 0, 0, 0);
  O = __builtin_amdgcn_mfma_f32_32x32x16_bf16(__builtin_bit_cast(short8, q2), lt1, O, 0, 0, 0);
  return O;
}

__global__ __launch_bounds__(256, 2) void k_main(const __hip_bfloat16* __restrict__ featU,
                                                 const __hip_bfloat16* __restrict__ featB,
                                                 const short8* __restrict__ LbfT,
                                                 float* __restrict__ slab) {
  __shared__ __align__(16) char ldsA[2][8192];  // 32 j-rows x 256 B, XOR-swizzled
  __shared__ __align__(16) char ldsL[2][2048];  // [jh][hi][c][idx8] bf16, linear
  const int tid  = threadIdx.x;
  const int lane = tid & 63, wid = tid >> 6;
  const int il   = lane & 31, hi = lane >> 5;
  const int wbase = blockIdx.x * 256 + wid * 64;
  const int split = blockIdx.y;

  const short8* fb0 = (const short8*)(featB + (size_t)(wbase + il) * DIM);
  const short8* fb1 = (const short8*)(featB + (size_t)(wbase + 32 + il) * DIM);
  short8 bfrag0[8], bfrag1[8];
#pragma unroll
  for (int kk = 0; kk < 8; ++kk) { bfrag0[kk] = fb0[kk * 2 + hi]; bfrag1[kk] = fb1[kk * 2 + hi]; }

  f32x16 O0, O1;
#pragma unroll
  for (int r = 0; r < 16; ++r) { O0[r] = 0.f; O1[r] = 0.f; }

  // staging slots (A swizzle: byte col ^= (row&15)<<4; L linear)
  const int r0 = tid >> 4, s0 = tid & 15, r1 = r0 + 16;
  const int offA0 = r0 * 256 + ((s0 * 16) ^ ((r0 & 15) << 4));
  const int offA1 = r1 * 256 + ((s0 * 16) ^ ((r1 & 15) << 4));

  {
    const short8* sA = (const short8*)(featU + (size_t)split * 32 * DIM);
    *(short8*)(&ldsA[0][offA0]) = sA[r0 * 16 + s0];
    *(short8*)(&ldsA[0][offA1]) = sA[r1 * 16 + s0];
    if (tid < 128) *(short8*)(&ldsL[0][tid * 16]) = LbfT[(size_t)split * 128 + tid];
  }
  __syncthreads();

  int cur = 0;
  for (int t = split; t < NT; t += CS) {
    const int tn = t + CS;
    const bool pf = tn < NT;
    short8 vA0, vA1, vL;
    if (pf) {  // issue next-tile loads early; latency hides under MFMA+exp
      const short8* sA = (const short8*)(featU + (size_t)tn * 32 * DIM);
      vA0 = sA[r0 * 16 + s0];
      vA1 = sA[r1 * 16 + s0];
      if (tid < 128) vL = LbfT[(size_t)tn * 128 + tid];
    }

    f32x16 D0, D1;
#pragma unroll
    for (int r = 0; r < 16; ++r) { D0[r] = 0.f; D1[r] = 0.f; }
    __builtin_amdgcn_s_setprio(1);
#pragma unroll
    for (int kk = 0; kk < 8; ++kk) {
      int off = il * 256 + (((kk * 32) + hi * 16) ^ ((il & 15) << 4));
      short8 a = *(const short8*)(&ldsA[cur][off]);   // A shared by both strips
      D0 = __builtin_amdgcn_mfma_f32_32x32x16_bf16(a, bfrag0[kk], D0, 0, 0, 0);
      D1 = __builtin_amdgcn_mfma_f32_32x32x16_bf16(a, bfrag1[kk], D1, 0, 0, 0);
    }
    __builtin_amdgcn_s_setprio(0);

    // one-hot B-frags (shared by both strips): lane reads [jh][hi][c=il][8]
    short8 lt0 = *(const short8*)(&ldsL[cur][hi * 512 + il * 16]);
    short8 lt1 = *(const short8*)(&ldsL[cur][1024 + hi * 512 + il * 16]);

    O0 = pvstep(D0, lt0, lt1, O0);
    O1 = pvstep(D1, lt0, lt1, O1);

    if (pf) {
      *(short8*)(&ldsA[cur ^ 1][offA0]) = vA0;
      *(short8*)(&ldsA[cur ^ 1][offA1]) = vA1;
      if (tid < 128) *(short8*)(&ldsL[cur ^ 1][tid * 16]) = vL;
    }
    __syncthreads();
    cur ^= 1;
  }

  // O layout: col = lane&31 = class, row = (reg&3)+8*(reg>>2)+4*hi = i-offset
  if (il < NCLS) {
#pragma unroll
    for (int reg = 0; reg < 16; ++reg) {
      int ioff = (reg & 3) + 8 * (reg >> 2) + 4 * hi;
      slab[((size_t)split * NCLS + il) * NROWS + wbase + ioff] = O0[reg];
      slab[((size_t)split * NCLS + il) * NROWS + wbase + 32 + ioff] = O1[reg];
    }
  }
}

// ---------- kernel 3: slab reduce (wide) + per-row loss + final reduce ----------
// 64 blocks x 256 thr; block owns 128 rows. Phase 1: coalesced split-sums into
// LDS. Phase 2: per-row loss. Last block folds partials (deterministic order).
__global__ void k_fin(const float* __restrict__ slab, const float* __restrict__ diag,
                      const int* __restrict__ cls, const int* __restrict__ histg,
                      float* __restrict__ partials, int* __restrict__ counter,
                      float* __restrict__ out) {
  __shared__ float ssum[NCLS][128];
  __shared__ int hcnt[128][NCLS];
  __shared__ float red[128];
  const int tid = threadIdx.x;
  const int b = blockIdx.x;
  // class counts (redundant per block): reduce 128 chunk-hists
  if (tid < 128) {
#pragma unroll
    for (int c = 0; c < NCLS; ++c) hcnt[tid][c] = histg[tid * NCLS + c];
  }
  __syncthreads();
  for (int st = 64; st > 0; st >>= 1) {
    if (tid < st) {
#pragma unroll
      for (int c = 0; c < NCLS; ++c) hcnt[tid][c] += hcnt[tid + st][c];
    }
    __syncthreads();
  }
  // phase 1: sum slab over splits for this block's 128 rows x 10 classes
#pragma unroll
  for (int pp = 0; pp < 5; ++pp) {
    int p = tid + pp * 256;            // p in [0,1280): c = p>>7, ii = p&127
    int c = p >> 7, ii = p & 127;
    float s = 0.f;
#pragma unroll
    for (int sp = 0; sp < CS; ++sp)
      s += slab[((size_t)sp * NCLS + c) * NROWS + b * 128 + ii];
    ssum[c][ii] = s;
  }
  __syncthreads();
  // phase 2: per-row loss
  if (tid < 128) {
    const int i = b * 128 + tid;
    const int ci = cls[i];
    const float self = diag[i];
    float L[NCLS];
    float mx = -1e30f;
#pragma unroll
    for (int c = 0; c < NCLS; ++c) {
      float sc = ssum[c][tid] - ((c == ci) ? self : 0.f);
      float py = (float)hcnt[0][c] - ((c == ci) ? 1.f : 0.f);
      L[c] = __logf(sc) - __logf(py);
      mx = fmaxf(mx, L[c]);
    }
    float sum = 0.f, Lt = 0.f;
#pragma unroll
    for (int c = 0; c < NCLS; ++c) {
      sum += __expf(L[c] - mx);
      Lt += (c == ci) ? L[c] : 0.f;
    }
    const float lse = mx + __logf(sum);
    red[tid] = (i >= NCLS) ? (lse - Lt) : 0.f;
  }
  __syncthreads();
  for (int st = 64; st > 0; st >>= 1) {
    if (tid < st) red[tid] += red[tid + st];
    __syncthreads();
  }
  if (tid == 0) {
    partials[b] = red[0];
    __threadfence();
    int old = atomicAdd(counter, 1);
    if (old == (int)gridDim.x - 1) {   // last block: deterministic fixed-order sum
      __threadfence();
      float t = 0.f;
      for (int bb = 0; bb < (int)gridDim.x; ++bb) t += partials[bb];
      out[0] = t / (float)(NROWS - NCLS);
    }
  }
}

extern "C" void kernel_launch(void* const* d_in, const int* in_sizes, int n_in,
                              void* d_out, int out_size, void* d_ws, size_t ws_size,
                              hipStream_t stream) {
  const float* label = (const float*)d_in[0];
  const float* feat  = (const float*)d_in[1];
  char* w = (char*)d_ws;
  __hip_bfloat16* featU = (__hip_bfloat16*)(w + OFF_FEATU);
  __hip_bfloat16* featB = (__hip_bfloat16*)(w + OFF_FEATB);
  short8* LbfT   = (short8*)(w + OFF_LBFT);
  float* slab    = (float*)(w + OFF_SLAB);
  float* diag    = (float*)(w + OFF_DIAG);
  int*   cls     = (int*)(w + OFF_CLS);
  int*   histg   = (int*)(w + OFF_HISTG);
  float* part    = (float*)(w + OFF_PART);
  int*   counter = (int*)(w + OFF_CNT);

  k_prep<<<1024, 256, 0, stream>>>(label, feat, featU, featB, LbfT, diag, cls, histg, counter);
  k_main<<<dim3(32, CS), 256, 0, stream>>>(featU, featB, LbfT, slab);
  k_fin<<<64, 256, 0, stream>>>(slab, diag, cls, histg, part, counter, (float*)d_out);
}